// Round 16
// baseline (1099.742 us; speedup 1.0000x reference)
//
#include <hip/hip_runtime.h>
#include <hip/hip_fp16.h>

#define N_NODES 50000
#define N_EDGES 800000
#define D 128
#define ED 64
#define NLAYERS 3

typedef __attribute__((ext_vector_type(8))) short s16x8;
typedef __attribute__((ext_vector_type(4))) float f32x4;
#define MFMA16 __builtin_amdgcn_mfma_f32_16x16x32_bf16

__device__ __forceinline__ unsigned short f2bf(float f) {
    unsigned int u = __float_as_uint(f);
    unsigned int r = (u + 0x7FFFu + ((u >> 16) & 1u)) >> 16;
    return (unsigned short)r;
}
__device__ __forceinline__ float bf2f(unsigned short h) {
    return __uint_as_float(((unsigned int)h) << 16);
}

// ---------------- prep kernels ----------------

__global__ void hist_kernel(const int* __restrict__ dst, int* __restrict__ deg) {
    int e = blockIdx.x * blockDim.x + threadIdx.x;
    if (e < N_EDGES) atomicAdd(&deg[dst[e]], 1);
}

__global__ void scan_kernel(int* __restrict__ deg_cursor, int* __restrict__ row_start) {
    __shared__ int part[1024];
    const int t = threadIdx.x;
    const int CH = (N_NODES + 1023) / 1024;  // 49
    int a = t * CH;
    int b = min(a + CH, N_NODES);
    int s = 0;
    for (int i = a; i < b; ++i) s += deg_cursor[i];
    part[t] = s;
    __syncthreads();
    for (int off = 1; off < 1024; off <<= 1) {
        int v = (t >= off) ? part[t - off] : 0;
        __syncthreads();
        part[t] += v;
        __syncthreads();
    }
    int base = (t == 0) ? 0 : part[t - 1];
    for (int i = a; i < b; ++i) {
        int d = deg_cursor[i];
        row_start[i] = base;
        deg_cursor[i] = base;
        base += d;
    }
    if (t == 1023) row_start[N_NODES] = part[1023];
}

__global__ void scatter_kernel(const int* __restrict__ dst, int* __restrict__ cursor,
                               int* __restrict__ perm) {
    int e = blockIdx.x * blockDim.x + threadIdx.x;
    if (e < N_EDGES) {
        int pos = atomicAdd(&cursor[dst[e]], 1);
        perm[pos] = e;
    }
}

// reorder into dst-sorted order; emit ea as bf16 hi/lo + sorted src/dst.
__global__ void reorder_kernel(const float4* __restrict__ ea, const int* __restrict__ perm,
                               const int* __restrict__ src, const int* __restrict__ dst,
                               unsigned short* __restrict__ eahi, unsigned short* __restrict__ ealo,
                               int* __restrict__ srcd, int* __restrict__ dstd) {
    int idx = blockIdx.x * blockDim.x + threadIdx.x;
    int i = idx >> 2, q = idx & 3;
    if (i < N_EDGES) {
        int pe = perm[i];
        const float4* srow = ea + (size_t)pe * (ED / 4) + q * 4;
        float f[16];
        #pragma unroll
        for (int j = 0; j < 4; ++j) {
            float4 v = srow[j];
            f[j * 4 + 0] = v.x; f[j * 4 + 1] = v.y; f[j * 4 + 2] = v.z; f[j * 4 + 3] = v.w;
        }
        s16x8 h0, h1, l0, l1;
        #pragma unroll
        for (int j = 0; j < 8; ++j) {
            unsigned short h = f2bf(f[j]);
            h0[j] = (short)h; l0[j] = (short)f2bf(f[j] - bf2f(h));
        }
        #pragma unroll
        for (int j = 0; j < 8; ++j) {
            unsigned short h = f2bf(f[8 + j]);
            h1[j] = (short)h; l1[j] = (short)f2bf(f[8 + j] - bf2f(h));
        }
        size_t o = (size_t)i * ED + q * 16;
        *(s16x8*)&eahi[o] = h0; *(s16x8*)&eahi[o + 8] = h1;
        *(s16x8*)&ealo[o] = l0; *(s16x8*)&ealo[o + 8] = l1;
        if (q == 0) { srcd[i] = src[pe]; dstd[i] = dst[pe]; }
    }
}

// Wsrc[L][K][C] -> transposed bf16 hi/lo T[L][C][K]
__global__ void wconvT_kernel(const float* __restrict__ Wsrc,
                              unsigned short* __restrict__ Thi,
                              unsigned short* __restrict__ Tlo,
                              int L, int K, int C) {
    int idx = blockIdx.x * 256 + threadIdx.x;
    if (idx < L * K * C) {
        int l = idx / (K * C);
        int rem = idx % (K * C);
        int k = rem / C, c = rem % C;
        float f = Wsrc[idx];
        unsigned short h = f2bf(f);
        unsigned short lo = f2bf(f - bf2f(h));
        int o = (l * C + c) * K + k;
        Thi[o] = h; Tlo[o] = lo;
    }
}

// ---------------- fused edge pass, v3: zero-barrier wave-independent pipelines ----------------
// Each wave owns 32 dst-sorted edges end-to-end: A-frags loaded DIRECTLY from
// the sorted bf16 hi/lo global stream (16B/lane contiguous, no LDS staging),
// 48 MFMA, fp16 msg -> wave-PRIVATE LDS tile rows (transpose), prefetched
// segmented-reduce epilogue. No __syncthreads at all; LDS = 32 KB msg tile.

template<int DIRECT>
__global__ __launch_bounds__(256, 5)
void edge_fused_kernel(const float* __restrict__ x,
                       const unsigned short* __restrict__ eahi,
                       const unsigned short* __restrict__ ealo,
                       const float* __restrict__ eaF,
                       const int* __restrict__ permN,
                       const int* __restrict__ srcd,
                       const int* __restrict__ dstd,
                       const unsigned short* __restrict__ WThi,
                       const unsigned short* __restrict__ WTlo,
                       const float* __restrict__ be,
                       float* __restrict__ hpre)
{
    __shared__ __half sM[128 * 128];     // 32768 B; wave w uses rows [32w,32w+32) only

    const int t = threadIdx.x;
    const int e0 = blockIdx.x * 128;
    const int w = t >> 6, l = t & 63;
    const int li = l & 15, lk = l >> 4;
    const int erow0 = w * 32;

    // epilogue metadata: lanes 0..31 hold this wave's 32 rows' src/dst
    int myS = 0, myD = 0;
    if (l < 32) {
        myS = srcd[e0 + erow0 + l];
        myD = dstd[e0 + erow0 + l];
    }

    // ---- A-fragments straight from global (sorted stream, 16B/lane) ----
    s16x8 Ah[2][2], Al[2][2];
    if (DIRECT) {
        #pragma unroll
        for (int r = 0; r < 2; ++r)
            #pragma unroll
            for (int s = 0; s < 2; ++s) {
                const size_t gb = (size_t)(e0 + erow0 + r * 16 + li) * ED + s * 32 + lk * 8;
                Ah[r][s] = *(const s16x8*)&eahi[gb];
                Al[r][s] = *(const s16x8*)&ealo[gb];
            }
    } else {
        const int pe0 = permN[e0 + erow0 + li];
        const int pe1 = permN[e0 + erow0 + 16 + li];
        #pragma unroll
        for (int r = 0; r < 2; ++r) {
            const int pe = r == 0 ? pe0 : pe1;
            #pragma unroll
            for (int s = 0; s < 2; ++s) {
                const float* base = &eaF[(size_t)pe * ED + s * 32 + lk * 8];
                float4 a = *(const float4*)base, b = *(const float4*)(base + 4);
                float f[8] = {a.x, a.y, a.z, a.w, b.x, b.y, b.z, b.w};
                s16x8 vh, vl;
                #pragma unroll
                for (int q = 0; q < 8; ++q) {
                    unsigned short h = f2bf(f[q]);
                    vh[q] = (short)h;
                    vl[q] = (short)f2bf(f[q] - bf2f(h));
                }
                Ah[r][s] = vh; Al[r][s] = vl;
            }
        }
    }

    // ---- GEMM: per col-tile, 6 MFMA, fp16 msg -> wave-private swizzled LDS rows ----
    #pragma unroll
    for (int c = 0; c < 8; ++c) {
        const int col = c * 16 + li;
        f32x4 acc0 = {0.f, 0.f, 0.f, 0.f}, acc1 = {0.f, 0.f, 0.f, 0.f};
        #pragma unroll
        for (int s = 0; s < 2; ++s) {
            const s16x8 Bh = *(const s16x8*)&WThi[col * ED + s * 32 + lk * 8];
            const s16x8 Bl = *(const s16x8*)&WTlo[col * ED + s * 32 + lk * 8];
            acc0 = MFMA16(Ah[0][s], Bh, acc0, 0, 0, 0);
            acc1 = MFMA16(Ah[1][s], Bh, acc1, 0, 0, 0);
            acc0 = MFMA16(Ah[0][s], Bl, acc0, 0, 0, 0);
            acc1 = MFMA16(Ah[1][s], Bl, acc1, 0, 0, 0);
            acc0 = MFMA16(Al[0][s], Bh, acc0, 0, 0, 0);
            acc1 = MFMA16(Al[1][s], Bh, acc1, 0, 0, 0);
        }
        const float bias = be[col];
        // D map [m89-verified]: col = lane&15, row = (lane>>4)*4 + reg
        #pragma unroll
        for (int reg = 0; reg < 4; ++reg) {
            const int r0 = erow0 + lk * 4 + reg;
            const int r1 = r0 + 16;
            sM[(r0 * 128 + col) ^ ((r0 & 7) << 3)] = __float2half(acc0[reg] + bias);
            sM[(r1 * 128 + col) ^ ((r1 & 7) << 3)] = __float2half(acc1[reg] + bias);
        }
    }
    // no barrier: wave reads only its own rows (intra-wave lgkmcnt ordering)

    // ---- segmented reduce: wave w owns rows [32w,32w+32), lane owns 2 cols ----
    {
        const int c0 = l * 2;
        const int rbase = erow0;
        float2 acc = make_float2(0.f, 0.f);
        int cur = __shfl(myD, 0);

        float2 xA0, xA1, xA2, xA3, xA4, xA5, xA6, xA7;
        float2 xB0, xB1, xB2, xB3, xB4, xB5, xB6, xB7;

#define LOADG(dst0,dst1,dst2,dst3,dst4,dst5,dst6,dst7, g)                          \
        do {                                                                       \
            dst0 = *(const float2*)&x[(size_t)__shfl(myS, (g)*8 + 0) * D + c0];    \
            dst1 = *(const float2*)&x[(size_t)__shfl(myS, (g)*8 + 1) * D + c0];    \
            dst2 = *(const float2*)&x[(size_t)__shfl(myS, (g)*8 + 2) * D + c0];    \
            dst3 = *(const float2*)&x[(size_t)__shfl(myS, (g)*8 + 3) * D + c0];    \
            dst4 = *(const float2*)&x[(size_t)__shfl(myS, (g)*8 + 4) * D + c0];    \
            dst5 = *(const float2*)&x[(size_t)__shfl(myS, (g)*8 + 5) * D + c0];    \
            dst6 = *(const float2*)&x[(size_t)__shfl(myS, (g)*8 + 6) * D + c0];    \
            dst7 = *(const float2*)&x[(size_t)__shfl(myS, (g)*8 + 7) * D + c0];    \
        } while (0)

#define PROC1(xv, rr)                                                              \
        do {                                                                       \
            const int row = rbase + (rr);                                          \
            const int dr = __shfl(myD, (rr));                                      \
            if (dr != cur) {                                                       \
                atomicAdd(&hpre[(size_t)cur * D + c0], acc.x);                     \
                atomicAdd(&hpre[(size_t)cur * D + c0 + 1], acc.y);                 \
                acc = make_float2(0.f, 0.f);                                       \
                cur = dr;                                                          \
            }                                                                      \
            float2 m = __half22float2(                                             \
                *(const __half2*)&sM[(row * 128 + c0) ^ ((row & 7) << 3)]);        \
            acc.x += fmaxf(m.x + xv.x, 0.f);                                       \
            acc.y += fmaxf(m.y + xv.y, 0.f);                                       \
        } while (0)

        LOADG(xA0,xA1,xA2,xA3,xA4,xA5,xA6,xA7, 0);
        LOADG(xB0,xB1,xB2,xB3,xB4,xB5,xB6,xB7, 1);
        PROC1(xA0, 0); PROC1(xA1, 1); PROC1(xA2, 2); PROC1(xA3, 3);
        PROC1(xA4, 4); PROC1(xA5, 5); PROC1(xA6, 6); PROC1(xA7, 7);
        LOADG(xA0,xA1,xA2,xA3,xA4,xA5,xA6,xA7, 2);
        PROC1(xB0, 8); PROC1(xB1, 9); PROC1(xB2,10); PROC1(xB3,11);
        PROC1(xB4,12); PROC1(xB5,13); PROC1(xB6,14); PROC1(xB7,15);
        LOADG(xB0,xB1,xB2,xB3,xB4,xB5,xB6,xB7, 3);
        PROC1(xA0,16); PROC1(xA1,17); PROC1(xA2,18); PROC1(xA3,19);
        PROC1(xA4,20); PROC1(xA5,21); PROC1(xA6,22); PROC1(xA7,23);
        PROC1(xB0,24); PROC1(xB1,25); PROC1(xB2,26); PROC1(xB3,27);
        PROC1(xB4,28); PROC1(xB5,29); PROC1(xB6,30); PROC1(xB7,31);

        atomicAdd(&hpre[(size_t)cur * D + c0], acc.x);
        atomicAdd(&hpre[(size_t)cur * D + c0 + 1], acc.y);
#undef LOADG
#undef PROC1
    }
}

// ---------------- fused MLP pair (MFMA) ----------------

__global__ __launch_bounds__(256, 5)
void mlp2_kernel(const float* __restrict__ in,
                 const unsigned short* __restrict__ W1h, const unsigned short* __restrict__ W1l,
                 const float* __restrict__ b1,
                 const unsigned short* __restrict__ W2h, const unsigned short* __restrict__ W2l,
                 const float* __restrict__ b2,
                 float* __restrict__ out, int relu2)
{
    __shared__ unsigned short sHi[64 * D];   // 16384 B, swizzled rows
    __shared__ unsigned short sLo[64 * D];
    const int t = threadIdx.x;
    const int n0 = blockIdx.x * 64;

    {
        const int r = t >> 2, k0 = (t & 3) * 32;
        const int gr = n0 + r;
        const int swz = (r & 7) << 3;
        #pragma unroll
        for (int j = 0; j < 4; ++j) {
            s16x8 vh = {0,0,0,0,0,0,0,0}, vl = {0,0,0,0,0,0,0,0};
            if (gr < N_NODES) {
                const float4* s4 = (const float4*)&in[(size_t)gr * D + k0];
                float4 va = s4[j * 2], vb = s4[j * 2 + 1];
                float f[8] = {va.x, va.y, va.z, va.w, vb.x, vb.y, vb.z, vb.w};
                #pragma unroll
                for (int q = 0; q < 8; ++q) {
                    unsigned short h = f2bf(f[q]);
                    vh[q] = (short)h;
                    vl[q] = (short)f2bf(f[q] - bf2f(h));
                }
            }
            *(s16x8*)&sHi[(r * D + k0 + j * 8) ^ swz] = vh;
            *(s16x8*)&sLo[(r * D + k0 + j * 8) ^ swz] = vl;
        }
    }
    __syncthreads();

    const int w = t >> 6, l = t & 63;
    const int li = l & 15, lk = l >> 4;
    const int row0 = w * 16;

    s16x8 Ah[4], Al[4];
    #pragma unroll
    for (int s = 0; s < 4; ++s) {
        const int row = row0 + li;
        const int idx = (row * D + s * 32 + lk * 8) ^ ((row & 7) << 3);
        Ah[s] = *(const s16x8*)&sHi[idx];
        Al[s] = *(const s16x8*)&sLo[idx];
    }
    __syncthreads();

    #pragma unroll
    for (int c = 0; c < 8; ++c) {
        const int col = c * 16 + li;
        f32x4 acc = {0.f, 0.f, 0.f, 0.f};
        #pragma unroll
        for (int s = 0; s < 4; ++s) {
            const s16x8 Bh = *(const s16x8*)&W1h[col * D + s * 32 + lk * 8];
            const s16x8 Bl = *(const s16x8*)&W1l[col * D + s * 32 + lk * 8];
            acc = MFMA16(Ah[s], Bh, acc, 0, 0, 0);
            acc = MFMA16(Ah[s], Bl, acc, 0, 0, 0);
            acc = MFMA16(Al[s], Bh, acc, 0, 0, 0);
        }
        const float bb = b1[col];
        #pragma unroll
        for (int reg = 0; reg < 4; ++reg) {
            const int row = row0 + lk * 4 + reg;
            float v = fmaxf(acc[reg] + bb, 0.f);
            unsigned short h = f2bf(v);
            const int idx = (row * D + col) ^ ((row & 7) << 3);
            sHi[idx] = h;
            sLo[idx] = f2bf(v - bf2f(h));
        }
    }
    __syncthreads();

    s16x8 Ch[4], Cl[4];
    #pragma unroll
    for (int s = 0; s < 4; ++s) {
        const int row = row0 + li;
        const int idx = (row * D + s * 32 + lk * 8) ^ ((row & 7) << 3);
        Ch[s] = *(const s16x8*)&sHi[idx];
        Cl[s] = *(const s16x8*)&sLo[idx];
    }

    #pragma unroll
    for (int c = 0; c < 8; ++c) {
        const int col = c * 16 + li;
        f32x4 acc = {0.f, 0.f, 0.f, 0.f};
        #pragma unroll
        for (int s = 0; s < 4; ++s) {
            const s16x8 Bh = *(const s16x8*)&W2h[col * D + s * 32 + lk * 8];
            const s16x8 Bl = *(const s16x8*)&W2l[col * D + s * 32 + lk * 8];
            acc = MFMA16(Ch[s], Bh, acc, 0, 0, 0);
            acc = MFMA16(Ch[s], Bl, acc, 0, 0, 0);
            acc = MFMA16(Cl[s], Bh, acc, 0, 0, 0);
        }
        const float bb = b2[col];
        #pragma unroll
        for (int reg = 0; reg < 4; ++reg) {
            const int gr = n0 + row0 + lk * 4 + reg;
            if (gr < N_NODES) {
                float v = acc[reg] + bb;
                if (relu2) v = fmaxf(v, 0.f);
                out[(size_t)gr * D + col] = v;
            }
        }
    }
}

// ---------------- host ----------------

extern "C" void kernel_launch(void* const* d_in, const int* in_sizes, int n_in,
                              void* d_out, int out_size, void* d_ws, size_t ws_size,
                              hipStream_t stream) {
    const float* x  = (const float*)d_in[0];
    const int*   ei = (const int*)d_in[1];
    const float* ea = (const float*)d_in[2];
    const float* We = (const float*)d_in[3];
    const float* be = (const float*)d_in[4];
    const float* W1 = (const float*)d_in[5];
    const float* b1 = (const float*)d_in[6];
    const float* W2 = (const float*)d_in[7];
    const float* b2 = (const float*)d_in[8];
    float* out = (float*)d_out;

    const int* src = ei;
    const int* dst = ei + N_EDGES;

    char* ws = (char*)d_ws;
    size_t off = 0;
    auto alloc = [&](size_t bytes) -> char* {
        char* p = ws + off;
        off = (off + bytes + 255) & ~(size_t)255;
        return p;
    };
    float* P          = (float*)alloc((size_t)N_NODES * D * 4);
    float* H          = (float*)alloc((size_t)N_NODES * D * 4);
    int*   perm       = (int*)alloc((size_t)N_EDGES * 4);
    int*   row_start  = (int*)alloc((size_t)(N_NODES + 1) * 4);
    int*   cursor     = (int*)alloc((size_t)N_NODES * 4);
    int*   srcd       = (int*)alloc((size_t)N_EDGES * 4);
    int*   dstd       = (int*)alloc((size_t)N_EDGES * 4);
    unsigned short* WeThi = (unsigned short*)alloc((size_t)NLAYERS * D * ED * 2);
    unsigned short* WeTlo = (unsigned short*)alloc((size_t)NLAYERS * D * ED * 2);
    unsigned short* W1Thi = (unsigned short*)alloc((size_t)NLAYERS * D * D * 2);
    unsigned short* W1Tlo = (unsigned short*)alloc((size_t)NLAYERS * D * D * 2);
    unsigned short* W2Thi = (unsigned short*)alloc((size_t)NLAYERS * D * D * 2);
    unsigned short* W2Tlo = (unsigned short*)alloc((size_t)NLAYERS * D * D * 2);
    unsigned short* eahi = (unsigned short*)alloc((size_t)N_EDGES * ED * 2);
    unsigned short* ealo = (unsigned short*)alloc((size_t)N_EDGES * ED * 2);
    bool direct = (off <= ws_size);
    (void)in_sizes; (void)n_in; (void)out_size;

    hipMemsetAsync(cursor, 0, N_NODES * 4, stream);
    hist_kernel<<<(N_EDGES + 255) / 256, 256, 0, stream>>>(dst, cursor);
    scan_kernel<<<1, 1024, 0, stream>>>(cursor, row_start);
    scatter_kernel<<<(N_EDGES + 255) / 256, 256, 0, stream>>>(dst, cursor, perm);
    reorder_kernel<<<(N_EDGES * 4 + 255) / 256, 256, 0, stream>>>(
        (const float4*)ea, perm, src, dst, eahi, ealo, srcd, dstd);
    wconvT_kernel<<<(NLAYERS * ED * D + 255) / 256, 256, 0, stream>>>(We, WeThi, WeTlo, NLAYERS, ED, D);
    wconvT_kernel<<<(NLAYERS * D * D + 255) / 256, 256, 0, stream>>>(W1, W1Thi, W1Tlo, NLAYERS, D, D);
    wconvT_kernel<<<(NLAYERS * D * D + 255) / 256, 256, 0, stream>>>(W2, W2Thi, W2Tlo, NLAYERS, D, D);

    const int ggrid = N_EDGES / 128;             // 6250
    const int mgrid = (N_NODES + 63) / 64;       // 782

    const float* X = x;
    for (int l = 0; l < NLAYERS; ++l) {
        const float* bel = be + (size_t)l * D;
        hipMemcpyAsync(P, (const void*)X, (size_t)N_NODES * D * 4,
                       hipMemcpyDeviceToDevice, stream);
        if (direct)
            edge_fused_kernel<1><<<ggrid, 256, 0, stream>>>(X, eahi, ealo, nullptr, nullptr,
                srcd, dstd, WeThi + (size_t)l * D * ED, WeTlo + (size_t)l * D * ED, bel, P);
        else
            edge_fused_kernel<0><<<ggrid, 256, 0, stream>>>(X, nullptr, nullptr, ea, perm,
                srcd, dstd, WeThi + (size_t)l * D * ED, WeTlo + (size_t)l * D * ED, bel, P);
        float* ob = (l < NLAYERS - 1) ? H : out;
        mlp2_kernel<<<mgrid, 256, 0, stream>>>(P,
            W1Thi + (size_t)l * D * D, W1Tlo + (size_t)l * D * D, b1 + (size_t)l * D,
            W2Thi + (size_t)l * D * D, W2Tlo + (size_t)l * D * D, b2 + (size_t)l * D,
            ob, (l < NLAYERS - 1) ? 1 : 0);
        X = H;
    }
}

// Round 17
// 1079.290 us; speedup vs baseline: 1.0189x; 1.0189x over previous
//
#include <hip/hip_runtime.h>
#include <hip/hip_fp16.h>

#define N_NODES 50000
#define N_EDGES 800000
#define D 128
#define ED 64
#define NLAYERS 3

typedef __attribute__((ext_vector_type(8))) short s16x8;
typedef __attribute__((ext_vector_type(4))) float f32x4;
#define MFMA16 __builtin_amdgcn_mfma_f32_16x16x32_bf16

__device__ __forceinline__ unsigned short f2bf(float f) {
    unsigned int u = __float_as_uint(f);
    unsigned int r = (u + 0x7FFFu + ((u >> 16) & 1u)) >> 16;
    return (unsigned short)r;
}
__device__ __forceinline__ float bf2f(unsigned short h) {
    return __uint_as_float(((unsigned int)h) << 16);
}

// ---------------- prep kernels ----------------

__global__ void hist_kernel(const int* __restrict__ dst, int* __restrict__ deg) {
    int e = blockIdx.x * blockDim.x + threadIdx.x;
    if (e < N_EDGES) atomicAdd(&deg[dst[e]], 1);
}

__global__ void scan_kernel(int* __restrict__ deg_cursor, int* __restrict__ row_start) {
    __shared__ int part[1024];
    const int t = threadIdx.x;
    const int CH = (N_NODES + 1023) / 1024;  // 49
    int a = t * CH;
    int b = min(a + CH, N_NODES);
    int s = 0;
    for (int i = a; i < b; ++i) s += deg_cursor[i];
    part[t] = s;
    __syncthreads();
    for (int off = 1; off < 1024; off <<= 1) {
        int v = (t >= off) ? part[t - off] : 0;
        __syncthreads();
        part[t] += v;
        __syncthreads();
    }
    int base = (t == 0) ? 0 : part[t - 1];
    for (int i = a; i < b; ++i) {
        int d = deg_cursor[i];
        row_start[i] = base;
        deg_cursor[i] = base;
        base += d;
    }
    if (t == 1023) row_start[N_NODES] = part[1023];
}

__global__ void scatter_kernel(const int* __restrict__ dst, int* __restrict__ cursor,
                               int* __restrict__ perm) {
    int e = blockIdx.x * blockDim.x + threadIdx.x;
    if (e < N_EDGES) {
        int pos = atomicAdd(&cursor[dst[e]], 1);
        perm[pos] = e;
    }
}

// FUSED scatter+reorder: sequential ea read, bf16 hi/lo split, random write at
// sorted position (atomic cursor). Random WRITES are fire-and-forget (vs the
// old random gather reads that stalled the reorder pass).
__global__ void reorder_fused_kernel(const float4* __restrict__ ea,
                                     const int* __restrict__ src, const int* __restrict__ dst,
                                     int* __restrict__ cursor,
                                     unsigned short* __restrict__ eahi, unsigned short* __restrict__ ealo,
                                     int* __restrict__ srcd, int* __restrict__ dstd) {
    int idx = blockIdx.x * blockDim.x + threadIdx.x;
    int i = idx >> 2, q = idx & 3;     // 4 lanes per edge
    if (i >= N_EDGES) return;
    const int l = threadIdx.x & 63;
    int pos = 0;
    if (q == 0) pos = atomicAdd(&cursor[dst[i]], 1);
    pos = __shfl(pos, (l >> 2) << 2);  // broadcast from q==0 lane of the 4-group

    const float4* srow = ea + (size_t)i * (ED / 4) + q * 4;
    float f[16];
    #pragma unroll
    for (int j = 0; j < 4; ++j) {
        float4 v = srow[j];
        f[j * 4 + 0] = v.x; f[j * 4 + 1] = v.y; f[j * 4 + 2] = v.z; f[j * 4 + 3] = v.w;
    }
    s16x8 h0, h1, l0, l1;
    #pragma unroll
    for (int j = 0; j < 8; ++j) {
        unsigned short h = f2bf(f[j]);
        h0[j] = (short)h; l0[j] = (short)f2bf(f[j] - bf2f(h));
    }
    #pragma unroll
    for (int j = 0; j < 8; ++j) {
        unsigned short h = f2bf(f[8 + j]);
        h1[j] = (short)h; l1[j] = (short)f2bf(f[8 + j] - bf2f(h));
    }
    size_t o = (size_t)pos * ED + q * 16;
    *(s16x8*)&eahi[o] = h0; *(s16x8*)&eahi[o + 8] = h1;
    *(s16x8*)&ealo[o] = l0; *(s16x8*)&ealo[o + 8] = l1;
    if (q == 0) { srcd[pos] = src[i]; dstd[pos] = dst[i]; }
}

// fallback (indirect) reorder via perm
__global__ void reorder_kernel(const float4* __restrict__ ea, const int* __restrict__ perm,
                               const int* __restrict__ src, const int* __restrict__ dst,
                               unsigned short* __restrict__ eahi, unsigned short* __restrict__ ealo,
                               int* __restrict__ srcd, int* __restrict__ dstd) {
    int idx = blockIdx.x * blockDim.x + threadIdx.x;
    int i = idx >> 2, q = idx & 3;
    if (i < N_EDGES) {
        int pe = perm[i];
        const float4* srow = ea + (size_t)pe * (ED / 4) + q * 4;
        float f[16];
        #pragma unroll
        for (int j = 0; j < 4; ++j) {
            float4 v = srow[j];
            f[j * 4 + 0] = v.x; f[j * 4 + 1] = v.y; f[j * 4 + 2] = v.z; f[j * 4 + 3] = v.w;
        }
        s16x8 h0, h1, l0, l1;
        #pragma unroll
        for (int j = 0; j < 8; ++j) {
            unsigned short h = f2bf(f[j]);
            h0[j] = (short)h; l0[j] = (short)f2bf(f[j] - bf2f(h));
        }
        #pragma unroll
        for (int j = 0; j < 8; ++j) {
            unsigned short h = f2bf(f[8 + j]);
            h1[j] = (short)h; l1[j] = (short)f2bf(f[8 + j] - bf2f(h));
        }
        size_t o = (size_t)i * ED + q * 16;
        *(s16x8*)&eahi[o] = h0; *(s16x8*)&eahi[o + 8] = h1;
        *(s16x8*)&ealo[o] = l0; *(s16x8*)&ealo[o + 8] = l1;
        if (q == 0) { srcd[i] = src[pe]; dstd[i] = dst[pe]; }
    }
}

// Wsrc[L][K][C] -> transposed bf16 hi/lo T[L][C][K]
__global__ void wconvT_kernel(const float* __restrict__ Wsrc,
                              unsigned short* __restrict__ Thi,
                              unsigned short* __restrict__ Tlo,
                              int L, int K, int C) {
    int idx = blockIdx.x * 256 + threadIdx.x;
    if (idx < L * K * C) {
        int l = idx / (K * C);
        int rem = idx % (K * C);
        int k = rem / C, c = rem % C;
        float f = Wsrc[idx];
        unsigned short h = f2bf(f);
        unsigned short lo = f2bf(f - bf2f(h));
        int o = (l * C + c) * K + k;
        Thi[o] = h; Tlo[o] = lo;
    }
}

// ---------------- fused edge pass (r15 structure, 3rd barrier removed) ----------------
// 128 dst-sorted edges/block, 4 waves, LDS 32 KB -> 5 blocks/CU, XOR-swizzle.
// Stage (cooperative, coalesced) -> barrier -> frags -> barrier -> GEMM ->
// wave-private msg rows (no barrier) -> shuffled-metadata prefetched epilogue.

template<int DIRECT>
__global__ __launch_bounds__(256, 5)
void edge_fused_kernel(const float* __restrict__ x,
                       const unsigned short* __restrict__ eahi,
                       const unsigned short* __restrict__ ealo,
                       const float* __restrict__ eaF,
                       const int* __restrict__ permN,
                       const int* __restrict__ srcd,
                       const int* __restrict__ dstd,
                       const unsigned short* __restrict__ WThi,
                       const unsigned short* __restrict__ WTlo,
                       const float* __restrict__ be,
                       float* __restrict__ hpre)
{
    __shared__ unsigned short sBuf[2 * 128 * ED];   // 32768 B exactly
    unsigned short* sAhi = sBuf;
    unsigned short* sAlo = sBuf + 128 * ED;
    __half* sM = (__half*)sBuf;                      // aliased msg tile [128][128] swizzled

    const int t = threadIdx.x;
    const int e0 = blockIdx.x * 128;

    // ---- stage ----
    {
        const int el = t >> 1, k0 = (t & 1) * 32;
        const int swz = (el & 7) << 3;
        if (DIRECT) {
            const size_t gb = (size_t)(e0 + el) * ED + k0;
            #pragma unroll
            for (int j = 0; j < 4; ++j) {
                s16x8 vh = *(const s16x8*)&eahi[gb + j * 8];
                s16x8 vl = *(const s16x8*)&ealo[gb + j * 8];
                *(s16x8*)&sAhi[(el * ED + k0 + j * 8) ^ swz] = vh;
                *(s16x8*)&sAlo[(el * ED + k0 + j * 8) ^ swz] = vl;
            }
        } else {
            const int pe = permN[e0 + el];
            const float4* s4 = (const float4*)&eaF[(size_t)pe * ED + k0];
            #pragma unroll
            for (int j = 0; j < 4; ++j) {
                float4 va = s4[j * 2], vb = s4[j * 2 + 1];
                float f[8] = {va.x, va.y, va.z, va.w, vb.x, vb.y, vb.z, vb.w};
                s16x8 vh, vl;
                #pragma unroll
                for (int q = 0; q < 8; ++q) {
                    unsigned short h = f2bf(f[q]);
                    vh[q] = (short)h;
                    vl[q] = (short)f2bf(f[q] - bf2f(h));
                }
                *(s16x8*)&sAhi[(el * ED + k0 + j * 8) ^ swz] = vh;
                *(s16x8*)&sAlo[(el * ED + k0 + j * 8) ^ swz] = vl;
            }
        }
    }

    const int w = t >> 6, l = t & 63;
    const int li = l & 15, lk = l >> 4;
    const int erow0 = w * 32;

    // epilogue metadata: lanes 0..31 load this wave's 32 rows' src/dst
    int myS = 0, myD = 0;
    if (l < 32) {
        myS = srcd[e0 + erow0 + l];
        myD = dstd[e0 + erow0 + l];
    }

    __syncthreads();

    s16x8 Ah[2][2], Al[2][2];
    #pragma unroll
    for (int r = 0; r < 2; ++r)
        #pragma unroll
        for (int s = 0; s < 2; ++s) {
            const int edge = erow0 + r * 16 + li;
            const int idx = (edge * ED + s * 32 + lk * 8) ^ ((edge & 7) << 3);
            Ah[r][s] = *(const s16x8*)&sAhi[idx];
            Al[r][s] = *(const s16x8*)&sAlo[idx];
        }
    __syncthreads();   // staging dead; LDS becomes msg tile

    // ---- GEMM: per col-tile, 6 MFMA, fp16 msg -> wave-private swizzled LDS rows ----
    #pragma unroll
    for (int c = 0; c < 8; ++c) {
        const int col = c * 16 + li;
        f32x4 acc0 = {0.f, 0.f, 0.f, 0.f}, acc1 = {0.f, 0.f, 0.f, 0.f};
        #pragma unroll
        for (int s = 0; s < 2; ++s) {
            const s16x8 Bh = *(const s16x8*)&WThi[col * ED + s * 32 + lk * 8];
            const s16x8 Bl = *(const s16x8*)&WTlo[col * ED + s * 32 + lk * 8];
            acc0 = MFMA16(Ah[0][s], Bh, acc0, 0, 0, 0);
            acc1 = MFMA16(Ah[1][s], Bh, acc1, 0, 0, 0);
            acc0 = MFMA16(Ah[0][s], Bl, acc0, 0, 0, 0);
            acc1 = MFMA16(Ah[1][s], Bl, acc1, 0, 0, 0);
            acc0 = MFMA16(Al[0][s], Bh, acc0, 0, 0, 0);
            acc1 = MFMA16(Al[1][s], Bh, acc1, 0, 0, 0);
        }
        const float bias = be[col];
        // D map [m89-verified]: col = lane&15, row = (lane>>4)*4 + reg
        #pragma unroll
        for (int reg = 0; reg < 4; ++reg) {
            const int r0 = erow0 + lk * 4 + reg;
            const int r1 = r0 + 16;
            sM[(r0 * 128 + col) ^ ((r0 & 7) << 3)] = __float2half(acc0[reg] + bias);
            sM[(r1 * 128 + col) ^ ((r1 & 7) << 3)] = __float2half(acc1[reg] + bias);
        }
    }
    // NO barrier: each wave reads only its own 32 msg rows (intra-wave lgkmcnt)

    // ---- segmented reduce: wave w owns rows [32w,32w+32), lane owns 2 cols ----
    {
        const int c0 = l * 2;
        const int rbase = erow0;
        float2 acc = make_float2(0.f, 0.f);
        int cur = __shfl(myD, 0);

        float2 xA0, xA1, xA2, xA3, xA4, xA5, xA6, xA7;
        float2 xB0, xB1, xB2, xB3, xB4, xB5, xB6, xB7;

#define LOADG(dst0,dst1,dst2,dst3,dst4,dst5,dst6,dst7, g)                          \
        do {                                                                       \
            dst0 = *(const float2*)&x[(size_t)__shfl(myS, (g)*8 + 0) * D + c0];    \
            dst1 = *(const float2*)&x[(size_t)__shfl(myS, (g)*8 + 1) * D + c0];    \
            dst2 = *(const float2*)&x[(size_t)__shfl(myS, (g)*8 + 2) * D + c0];    \
            dst3 = *(const float2*)&x[(size_t)__shfl(myS, (g)*8 + 3) * D + c0];    \
            dst4 = *(const float2*)&x[(size_t)__shfl(myS, (g)*8 + 4) * D + c0];    \
            dst5 = *(const float2*)&x[(size_t)__shfl(myS, (g)*8 + 5) * D + c0];    \
            dst6 = *(const float2*)&x[(size_t)__shfl(myS, (g)*8 + 6) * D + c0];    \
            dst7 = *(const float2*)&x[(size_t)__shfl(myS, (g)*8 + 7) * D + c0];    \
        } while (0)

#define PROC1(xv, rr)                                                              \
        do {                                                                       \
            const int row = rbase + (rr);                                          \
            const int dr = __shfl(myD, (rr));                                      \
            if (dr != cur) {                                                       \
                atomicAdd(&hpre[(size_t)cur * D + c0], acc.x);                     \
                atomicAdd(&hpre[(size_t)cur * D + c0 + 1], acc.y);                 \
                acc = make_float2(0.f, 0.f);                                       \
                cur = dr;                                                          \
            }                                                                      \
            float2 m = __half22float2(                                             \
                *(const __half2*)&sM[(row * 128 + c0) ^ ((row & 7) << 3)]);        \
            acc.x += fmaxf(m.x + xv.x, 0.f);                                       \
            acc.y += fmaxf(m.y + xv.y, 0.f);                                       \
        } while (0)

        LOADG(xA0,xA1,xA2,xA3,xA4,xA5,xA6,xA7, 0);
        LOADG(xB0,xB1,xB2,xB3,xB4,xB5,xB6,xB7, 1);
        PROC1(xA0, 0); PROC1(xA1, 1); PROC1(xA2, 2); PROC1(xA3, 3);
        PROC1(xA4, 4); PROC1(xA5, 5); PROC1(xA6, 6); PROC1(xA7, 7);
        LOADG(xA0,xA1,xA2,xA3,xA4,xA5,xA6,xA7, 2);
        PROC1(xB0, 8); PROC1(xB1, 9); PROC1(xB2,10); PROC1(xB3,11);
        PROC1(xB4,12); PROC1(xB5,13); PROC1(xB6,14); PROC1(xB7,15);
        LOADG(xB0,xB1,xB2,xB3,xB4,xB5,xB6,xB7, 3);
        PROC1(xA0,16); PROC1(xA1,17); PROC1(xA2,18); PROC1(xA3,19);
        PROC1(xA4,20); PROC1(xA5,21); PROC1(xA6,22); PROC1(xA7,23);
        PROC1(xB0,24); PROC1(xB1,25); PROC1(xB2,26); PROC1(xB3,27);
        PROC1(xB4,28); PROC1(xB5,29); PROC1(xB6,30); PROC1(xB7,31);

        atomicAdd(&hpre[(size_t)cur * D + c0], acc.x);
        atomicAdd(&hpre[(size_t)cur * D + c0 + 1], acc.y);
#undef LOADG
#undef PROC1
    }
}

// ---------------- fused MLP pair (MFMA) ----------------

__global__ __launch_bounds__(256, 5)
void mlp2_kernel(const float* __restrict__ in,
                 const unsigned short* __restrict__ W1h, const unsigned short* __restrict__ W1l,
                 const float* __restrict__ b1,
                 const unsigned short* __restrict__ W2h, const unsigned short* __restrict__ W2l,
                 const float* __restrict__ b2,
                 float* __restrict__ out, int relu2)
{
    __shared__ unsigned short sHi[64 * D];   // 16384 B, swizzled rows
    __shared__ unsigned short sLo[64 * D];
    const int t = threadIdx.x;
    const int n0 = blockIdx.x * 64;

    {
        const int r = t >> 2, k0 = (t & 3) * 32;
        const int gr = n0 + r;
        const int swz = (r & 7) << 3;
        #pragma unroll
        for (int j = 0; j < 4; ++j) {
            s16x8 vh = {0,0,0,0,0,0,0,0}, vl = {0,0,0,0,0,0,0,0};
            if (gr < N_NODES) {
                const float4* s4 = (const float4*)&in[(size_t)gr * D + k0];
                float4 va = s4[j * 2], vb = s4[j * 2 + 1];
                float f[8] = {va.x, va.y, va.z, va.w, vb.x, vb.y, vb.z, vb.w};
                #pragma unroll
                for (int q = 0; q < 8; ++q) {
                    unsigned short h = f2bf(f[q]);
                    vh[q] = (short)h;
                    vl[q] = (short)f2bf(f[q] - bf2f(h));
                }
            }
            *(s16x8*)&sHi[(r * D + k0 + j * 8) ^ swz] = vh;
            *(s16x8*)&sLo[(r * D + k0 + j * 8) ^ swz] = vl;
        }
    }
    __syncthreads();

    const int w = t >> 6, l = t & 63;
    const int li = l & 15, lk = l >> 4;
    const int row0 = w * 16;

    s16x8 Ah[4], Al[4];
    #pragma unroll
    for (int s = 0; s < 4; ++s) {
        const int row = row0 + li;
        const int idx = (row * D + s * 32 + lk * 8) ^ ((row & 7) << 3);
        Ah[s] = *(const s16x8*)&sHi[idx];
        Al[s] = *(const s16x8*)&sLo[idx];
    }
    __syncthreads();

    #pragma unroll
    for (int c = 0; c < 8; ++c) {
        const int col = c * 16 + li;
        f32x4 acc = {0.f, 0.f, 0.f, 0.f};
        #pragma unroll
        for (int s = 0; s < 4; ++s) {
            const s16x8 Bh = *(const s16x8*)&W1h[col * D + s * 32 + lk * 8];
            const s16x8 Bl = *(const s16x8*)&W1l[col * D + s * 32 + lk * 8];
            acc = MFMA16(Ah[s], Bh, acc, 0, 0, 0);
            acc = MFMA16(Ah[s], Bl, acc, 0, 0, 0);
            acc = MFMA16(Al[s], Bh, acc, 0, 0, 0);
        }
        const float bb = b1[col];
        #pragma unroll
        for (int reg = 0; reg < 4; ++reg) {
            const int row = row0 + lk * 4 + reg;
            float v = fmaxf(acc[reg] + bb, 0.f);
            unsigned short h = f2bf(v);
            const int idx = (row * D + col) ^ ((row & 7) << 3);
            sHi[idx] = h;
            sLo[idx] = f2bf(v - bf2f(h));
        }
    }
    __syncthreads();

    s16x8 Ch[4], Cl[4];
    #pragma unroll
    for (int s = 0; s < 4; ++s) {
        const int row = row0 + li;
        const int idx = (row * D + s * 32 + lk * 8) ^ ((row & 7) << 3);
        Ch[s] = *(const s16x8*)&sHi[idx];
        Cl[s] = *(const s16x8*)&sLo[idx];
    }

    #pragma unroll
    for (int c = 0; c < 8; ++c) {
        const int col = c * 16 + li;
        f32x4 acc = {0.f, 0.f, 0.f, 0.f};
        #pragma unroll
        for (int s = 0; s < 4; ++s) {
            const s16x8 Bh = *(const s16x8*)&W2h[col * D + s * 32 + lk * 8];
            const s16x8 Bl = *(const s16x8*)&W2l[col * D + s * 32 + lk * 8];
            acc = MFMA16(Ch[s], Bh, acc, 0, 0, 0);
            acc = MFMA16(Ch[s], Bl, acc, 0, 0, 0);
            acc = MFMA16(Cl[s], Bh, acc, 0, 0, 0);
        }
        const float bb = b2[col];
        #pragma unroll
        for (int reg = 0; reg < 4; ++reg) {
            const int gr = n0 + row0 + lk * 4 + reg;
            if (gr < N_NODES) {
                float v = acc[reg] + bb;
                if (relu2) v = fmaxf(v, 0.f);
                out[(size_t)gr * D + col] = v;
            }
        }
    }
}

// ---------------- host ----------------

extern "C" void kernel_launch(void* const* d_in, const int* in_sizes, int n_in,
                              void* d_out, int out_size, void* d_ws, size_t ws_size,
                              hipStream_t stream) {
    const float* x  = (const float*)d_in[0];
    const int*   ei = (const int*)d_in[1];
    const float* ea = (const float*)d_in[2];
    const float* We = (const float*)d_in[3];
    const float* be = (const float*)d_in[4];
    const float* W1 = (const float*)d_in[5];
    const float* b1 = (const float*)d_in[6];
    const float* W2 = (const float*)d_in[7];
    const float* b2 = (const float*)d_in[8];
    float* out = (float*)d_out;

    const int* src = ei;
    const int* dst = ei + N_EDGES;

    char* ws = (char*)d_ws;
    size_t off = 0;
    auto alloc = [&](size_t bytes) -> char* {
        char* p = ws + off;
        off = (off + bytes + 255) & ~(size_t)255;
        return p;
    };
    float* P          = (float*)alloc((size_t)N_NODES * D * 4);
    float* H          = (float*)alloc((size_t)N_NODES * D * 4);
    int*   perm       = (int*)alloc((size_t)N_EDGES * 4);
    int*   row_start  = (int*)alloc((size_t)(N_NODES + 1) * 4);
    int*   cursor     = (int*)alloc((size_t)N_NODES * 4);
    int*   srcd       = (int*)alloc((size_t)N_EDGES * 4);
    int*   dstd       = (int*)alloc((size_t)N_EDGES * 4);
    unsigned short* WeThi = (unsigned short*)alloc((size_t)NLAYERS * D * ED * 2);
    unsigned short* WeTlo = (unsigned short*)alloc((size_t)NLAYERS * D * ED * 2);
    unsigned short* W1Thi = (unsigned short*)alloc((size_t)NLAYERS * D * D * 2);
    unsigned short* W1Tlo = (unsigned short*)alloc((size_t)NLAYERS * D * D * 2);
    unsigned short* W2Thi = (unsigned short*)alloc((size_t)NLAYERS * D * D * 2);
    unsigned short* W2Tlo = (unsigned short*)alloc((size_t)NLAYERS * D * D * 2);
    unsigned short* eahi = (unsigned short*)alloc((size_t)N_EDGES * ED * 2);
    unsigned short* ealo = (unsigned short*)alloc((size_t)N_EDGES * ED * 2);
    bool direct = (off <= ws_size);
    (void)in_sizes; (void)n_in; (void)out_size;

    hipMemsetAsync(cursor, 0, N_NODES * 4, stream);
    hist_kernel<<<(N_EDGES + 255) / 256, 256, 0, stream>>>(dst, cursor);
    scan_kernel<<<1, 1024, 0, stream>>>(cursor, row_start);
    if (direct) {
        // fused scatter+reorder: sequential read, atomic-cursor random write
        reorder_fused_kernel<<<(N_EDGES * 4 + 255) / 256, 256, 0, stream>>>(
            (const float4*)ea, src, dst, cursor, eahi, ealo, srcd, dstd);
    } else {
        scatter_kernel<<<(N_EDGES + 255) / 256, 256, 0, stream>>>(dst, cursor, perm);
        reorder_kernel<<<(N_EDGES * 4 + 255) / 256, 256, 0, stream>>>(
            (const float4*)ea, perm, src, dst, eahi, ealo, srcd, dstd);
    }
    wconvT_kernel<<<(NLAYERS * ED * D + 255) / 256, 256, 0, stream>>>(We, WeThi, WeTlo, NLAYERS, ED, D);
    wconvT_kernel<<<(NLAYERS * D * D + 255) / 256, 256, 0, stream>>>(W1, W1Thi, W1Tlo, NLAYERS, D, D);
    wconvT_kernel<<<(NLAYERS * D * D + 255) / 256, 256, 0, stream>>>(W2, W2Thi, W2Tlo, NLAYERS, D, D);

    const int ggrid = N_EDGES / 128;             // 6250
    const int mgrid = (N_NODES + 63) / 64;       // 782

    const float* X = x;
    for (int l = 0; l < NLAYERS; ++l) {
        const float* bel = be + (size_t)l * D;
        hipMemcpyAsync(P, (const void*)X, (size_t)N_NODES * D * 4,
                       hipMemcpyDeviceToDevice, stream);
        edge_fused_kernel<1><<<ggrid, 256, 0, stream>>>(X, eahi, ealo, nullptr, nullptr,
            srcd, dstd, WeThi + (size_t)l * D * ED, WeTlo + (size_t)l * D * ED, bel, P);
        float* ob = (l < NLAYERS - 1) ? H : out;
        mlp2_kernel<<<mgrid, 256, 0, stream>>>(P,
            W1Thi + (size_t)l * D * D, W1Tlo + (size_t)l * D * D, b1 + (size_t)l * D,
            W2Thi + (size_t)l * D * D, W2Tlo + (size_t)l * D * D, b2 + (size_t)l * D,
            ob, (l < NLAYERS - 1) ? 1 : 0);
        X = H;
    }
}

// Round 18
// 967.402 us; speedup vs baseline: 1.1368x; 1.1157x over previous
//
#include <hip/hip_runtime.h>
#include <hip/hip_fp16.h>

#define N_NODES 50000
#define N_EDGES 800000
#define D 128
#define ED 64
#define NLAYERS 3

typedef __attribute__((ext_vector_type(8))) short s16x8;
typedef __attribute__((ext_vector_type(4))) float f32x4;
#define MFMA16 __builtin_amdgcn_mfma_f32_16x16x32_bf16

__device__ __forceinline__ unsigned short f2bf(float f) {
    unsigned int u = __float_as_uint(f);
    unsigned int r = (u + 0x7FFFu + ((u >> 16) & 1u)) >> 16;
    return (unsigned short)r;
}
__device__ __forceinline__ float bf2f(unsigned short h) {
    return __uint_as_float(((unsigned int)h) << 16);
}

// ---------------- prep kernels ----------------

__global__ void hist_kernel(const int* __restrict__ dst, int* __restrict__ deg) {
    int e = blockIdx.x * blockDim.x + threadIdx.x;
    if (e < N_EDGES) atomicAdd(&deg[dst[e]], 1);
}

__global__ void scan_kernel(int* __restrict__ deg_cursor, int* __restrict__ row_start) {
    __shared__ int part[1024];
    const int t = threadIdx.x;
    const int CH = (N_NODES + 1023) / 1024;  // 49
    int a = t * CH;
    int b = min(a + CH, N_NODES);
    int s = 0;
    for (int i = a; i < b; ++i) s += deg_cursor[i];
    part[t] = s;
    __syncthreads();
    for (int off = 1; off < 1024; off <<= 1) {
        int v = (t >= off) ? part[t - off] : 0;
        __syncthreads();
        part[t] += v;
        __syncthreads();
    }
    int base = (t == 0) ? 0 : part[t - 1];
    for (int i = a; i < b; ++i) {
        int d = deg_cursor[i];
        row_start[i] = base;
        deg_cursor[i] = base;
        base += d;
    }
    if (t == 1023) row_start[N_NODES] = part[1023];
}

__global__ void scatter_kernel(const int* __restrict__ dst, int* __restrict__ cursor,
                               int* __restrict__ perm) {
    int e = blockIdx.x * blockDim.x + threadIdx.x;
    if (e < N_EDGES) {
        int pos = atomicAdd(&cursor[dst[e]], 1);
        perm[pos] = e;
    }
}

// FUSED scatter+reorder: sequential ea read, bf16 hi/lo split, random write at
// sorted position (atomic cursor).
__global__ void reorder_fused_kernel(const float4* __restrict__ ea,
                                     const int* __restrict__ src, const int* __restrict__ dst,
                                     int* __restrict__ cursor,
                                     unsigned short* __restrict__ eahi, unsigned short* __restrict__ ealo,
                                     int* __restrict__ srcd, int* __restrict__ dstd) {
    int idx = blockIdx.x * blockDim.x + threadIdx.x;
    int i = idx >> 2, q = idx & 3;     // 4 lanes per edge
    if (i >= N_EDGES) return;
    const int l = threadIdx.x & 63;
    int pos = 0;
    if (q == 0) pos = atomicAdd(&cursor[dst[i]], 1);
    pos = __shfl(pos, (l >> 2) << 2);  // broadcast from q==0 lane of the 4-group

    const float4* srow = ea + (size_t)i * (ED / 4) + q * 4;
    float f[16];
    #pragma unroll
    for (int j = 0; j < 4; ++j) {
        float4 v = srow[j];
        f[j * 4 + 0] = v.x; f[j * 4 + 1] = v.y; f[j * 4 + 2] = v.z; f[j * 4 + 3] = v.w;
    }
    s16x8 h0, h1, l0, l1;
    #pragma unroll
    for (int j = 0; j < 8; ++j) {
        unsigned short h = f2bf(f[j]);
        h0[j] = (short)h; l0[j] = (short)f2bf(f[j] - bf2f(h));
    }
    #pragma unroll
    for (int j = 0; j < 8; ++j) {
        unsigned short h = f2bf(f[8 + j]);
        h1[j] = (short)h; l1[j] = (short)f2bf(f[8 + j] - bf2f(h));
    }
    size_t o = (size_t)pos * ED + q * 16;
    *(s16x8*)&eahi[o] = h0; *(s16x8*)&eahi[o + 8] = h1;
    *(s16x8*)&ealo[o] = l0; *(s16x8*)&ealo[o + 8] = l1;
    if (q == 0) { srcd[pos] = src[i]; dstd[pos] = dst[i]; }
}

// fallback (indirect) reorder via perm
__global__ void reorder_kernel(const float4* __restrict__ ea, const int* __restrict__ perm,
                               const int* __restrict__ src, const int* __restrict__ dst,
                               unsigned short* __restrict__ eahi, unsigned short* __restrict__ ealo,
                               int* __restrict__ srcd, int* __restrict__ dstd) {
    int idx = blockIdx.x * blockDim.x + threadIdx.x;
    int i = idx >> 2, q = idx & 3;
    if (i < N_EDGES) {
        int pe = perm[i];
        const float4* srow = ea + (size_t)pe * (ED / 4) + q * 4;
        float f[16];
        #pragma unroll
        for (int j = 0; j < 4; ++j) {
            float4 v = srow[j];
            f[j * 4 + 0] = v.x; f[j * 4 + 1] = v.y; f[j * 4 + 2] = v.z; f[j * 4 + 3] = v.w;
        }
        s16x8 h0, h1, l0, l1;
        #pragma unroll
        for (int j = 0; j < 8; ++j) {
            unsigned short h = f2bf(f[j]);
            h0[j] = (short)h; l0[j] = (short)f2bf(f[j] - bf2f(h));
        }
        #pragma unroll
        for (int j = 0; j < 8; ++j) {
            unsigned short h = f2bf(f[8 + j]);
            h1[j] = (short)h; l1[j] = (short)f2bf(f[8 + j] - bf2f(h));
        }
        size_t o = (size_t)i * ED + q * 16;
        *(s16x8*)&eahi[o] = h0; *(s16x8*)&eahi[o + 8] = h1;
        *(s16x8*)&ealo[o] = l0; *(s16x8*)&ealo[o + 8] = l1;
        if (q == 0) { srcd[i] = src[pe]; dstd[i] = dst[pe]; }
    }
}

// Wsrc[L][K][C] -> transposed bf16 hi/lo T[L][C][K]
__global__ void wconvT_kernel(const float* __restrict__ Wsrc,
                              unsigned short* __restrict__ Thi,
                              unsigned short* __restrict__ Tlo,
                              int L, int K, int C) {
    int idx = blockIdx.x * 256 + threadIdx.x;
    if (idx < L * K * C) {
        int l = idx / (K * C);
        int rem = idx % (K * C);
        int k = rem / C, c = rem % C;
        float f = Wsrc[idx];
        unsigned short h = f2bf(f);
        unsigned short lo = f2bf(f - bf2f(h));
        int o = (l * C + c) * K + k;
        Thi[o] = h; Tlo[o] = lo;
    }
}

// ---------------- fused edge pass (exact r15 structure: ALL THREE barriers) ----------------
// 128 dst-sorted edges/block, 4 waves, LDS 32 KB -> 5 blocks/CU, XOR-swizzle.
// Barrier 3 (GEMM->epilogue) is LOAD-BEARING: removing it lets the compiler
// interleave x-gathers/atomics into the GEMM, evicting hpre RMW lines from L2
// (r17: FETCH +77MB, WRITE +125MB, dur +17%).

template<int DIRECT>
__global__ __launch_bounds__(256, 5)
void edge_fused_kernel(const float* __restrict__ x,
                       const unsigned short* __restrict__ eahi,
                       const unsigned short* __restrict__ ealo,
                       const float* __restrict__ eaF,
                       const int* __restrict__ permN,
                       const int* __restrict__ srcd,
                       const int* __restrict__ dstd,
                       const unsigned short* __restrict__ WThi,
                       const unsigned short* __restrict__ WTlo,
                       const float* __restrict__ be,
                       float* __restrict__ hpre)
{
    __shared__ unsigned short sBuf[2 * 128 * ED];   // 32768 B exactly
    unsigned short* sAhi = sBuf;
    unsigned short* sAlo = sBuf + 128 * ED;
    __half* sM = (__half*)sBuf;                      // aliased msg tile [128][128] swizzled

    const int t = threadIdx.x;
    const int e0 = blockIdx.x * 128;

    // ---- stage ----
    {
        const int el = t >> 1, k0 = (t & 1) * 32;
        const int swz = (el & 7) << 3;
        if (DIRECT) {
            const size_t gb = (size_t)(e0 + el) * ED + k0;
            #pragma unroll
            for (int j = 0; j < 4; ++j) {
                s16x8 vh = *(const s16x8*)&eahi[gb + j * 8];
                s16x8 vl = *(const s16x8*)&ealo[gb + j * 8];
                *(s16x8*)&sAhi[(el * ED + k0 + j * 8) ^ swz] = vh;
                *(s16x8*)&sAlo[(el * ED + k0 + j * 8) ^ swz] = vl;
            }
        } else {
            const int pe = permN[e0 + el];
            const float4* s4 = (const float4*)&eaF[(size_t)pe * ED + k0];
            #pragma unroll
            for (int j = 0; j < 4; ++j) {
                float4 va = s4[j * 2], vb = s4[j * 2 + 1];
                float f[8] = {va.x, va.y, va.z, va.w, vb.x, vb.y, vb.z, vb.w};
                s16x8 vh, vl;
                #pragma unroll
                for (int q = 0; q < 8; ++q) {
                    unsigned short h = f2bf(f[q]);
                    vh[q] = (short)h;
                    vl[q] = (short)f2bf(f[q] - bf2f(h));
                }
                *(s16x8*)&sAhi[(el * ED + k0 + j * 8) ^ swz] = vh;
                *(s16x8*)&sAlo[(el * ED + k0 + j * 8) ^ swz] = vl;
            }
        }
    }

    const int w = t >> 6, l = t & 63;
    const int li = l & 15, lk = l >> 4;
    const int erow0 = w * 32;

    // epilogue metadata: lanes 0..31 load this wave's 32 rows' src/dst
    int myS = 0, myD = 0;
    if (l < 32) {
        myS = srcd[e0 + erow0 + l];
        myD = dstd[e0 + erow0 + l];
    }

    __syncthreads();

    s16x8 Ah[2][2], Al[2][2];
    #pragma unroll
    for (int r = 0; r < 2; ++r)
        #pragma unroll
        for (int s = 0; s < 2; ++s) {
            const int edge = erow0 + r * 16 + li;
            const int idx = (edge * ED + s * 32 + lk * 8) ^ ((edge & 7) << 3);
            Ah[r][s] = *(const s16x8*)&sAhi[idx];
            Al[r][s] = *(const s16x8*)&sAlo[idx];
        }
    __syncthreads();   // staging dead; LDS becomes msg tile

    // ---- GEMM: per col-tile, 6 MFMA, fp16 msg -> swizzled LDS tile ----
    #pragma unroll
    for (int c = 0; c < 8; ++c) {
        const int col = c * 16 + li;
        f32x4 acc0 = {0.f, 0.f, 0.f, 0.f}, acc1 = {0.f, 0.f, 0.f, 0.f};
        #pragma unroll
        for (int s = 0; s < 2; ++s) {
            const s16x8 Bh = *(const s16x8*)&WThi[col * ED + s * 32 + lk * 8];
            const s16x8 Bl = *(const s16x8*)&WTlo[col * ED + s * 32 + lk * 8];
            acc0 = MFMA16(Ah[0][s], Bh, acc0, 0, 0, 0);
            acc1 = MFMA16(Ah[1][s], Bh, acc1, 0, 0, 0);
            acc0 = MFMA16(Ah[0][s], Bl, acc0, 0, 0, 0);
            acc1 = MFMA16(Ah[1][s], Bl, acc1, 0, 0, 0);
            acc0 = MFMA16(Al[0][s], Bh, acc0, 0, 0, 0);
            acc1 = MFMA16(Al[1][s], Bh, acc1, 0, 0, 0);
        }
        const float bias = be[col];
        // D map [m89-verified]: col = lane&15, row = (lane>>4)*4 + reg
        #pragma unroll
        for (int reg = 0; reg < 4; ++reg) {
            const int r0 = erow0 + lk * 4 + reg;
            const int r1 = r0 + 16;
            sM[(r0 * 128 + col) ^ ((r0 & 7) << 3)] = __float2half(acc0[reg] + bias);
            sM[(r1 * 128 + col) ^ ((r1 & 7) << 3)] = __float2half(acc1[reg] + bias);
        }
    }
    __syncthreads();   // LOAD-BEARING: keeps epilogue atomics out of the GEMM phase

    // ---- segmented reduce: wave w owns rows [32w,32w+32), lane owns 2 cols ----
    {
        const int c0 = l * 2;
        const int rbase = erow0;
        float2 acc = make_float2(0.f, 0.f);
        int cur = __shfl(myD, 0);

        float2 xA0, xA1, xA2, xA3, xA4, xA5, xA6, xA7;
        float2 xB0, xB1, xB2, xB3, xB4, xB5, xB6, xB7;

#define LOADG(dst0,dst1,dst2,dst3,dst4,dst5,dst6,dst7, g)                          \
        do {                                                                       \
            dst0 = *(const float2*)&x[(size_t)__shfl(myS, (g)*8 + 0) * D + c0];    \
            dst1 = *(const float2*)&x[(size_t)__shfl(myS, (g)*8 + 1) * D + c0];    \
            dst2 = *(const float2*)&x[(size_t)__shfl(myS, (g)*8 + 2) * D + c0];    \
            dst3 = *(const float2*)&x[(size_t)__shfl(myS, (g)*8 + 3) * D + c0];    \
            dst4 = *(const float2*)&x[(size_t)__shfl(myS, (g)*8 + 4) * D + c0];    \
            dst5 = *(const float2*)&x[(size_t)__shfl(myS, (g)*8 + 5) * D + c0];    \
            dst6 = *(const float2*)&x[(size_t)__shfl(myS, (g)*8 + 6) * D + c0];    \
            dst7 = *(const float2*)&x[(size_t)__shfl(myS, (g)*8 + 7) * D + c0];    \
        } while (0)

#define PROC1(xv, rr)                                                              \
        do {                                                                       \
            const int row = rbase + (rr);                                          \
            const int dr = __shfl(myD, (rr));                                      \
            if (dr != cur) {                                                       \
                atomicAdd(&hpre[(size_t)cur * D + c0], acc.x);                     \
                atomicAdd(&hpre[(size_t)cur * D + c0 + 1], acc.y);                 \
                acc = make_float2(0.f, 0.f);                                       \
                cur = dr;                                                          \
            }                                                                      \
            float2 m = __half22float2(                                             \
                *(const __half2*)&sM[(row * 128 + c0) ^ ((row & 7) << 3)]);        \
            acc.x += fmaxf(m.x + xv.x, 0.f);                                       \
            acc.y += fmaxf(m.y + xv.y, 0.f);                                       \
        } while (0)

        LOADG(xA0,xA1,xA2,xA3,xA4,xA5,xA6,xA7, 0);
        LOADG(xB0,xB1,xB2,xB3,xB4,xB5,xB6,xB7, 1);
        PROC1(xA0, 0); PROC1(xA1, 1); PROC1(xA2, 2); PROC1(xA3, 3);
        PROC1(xA4, 4); PROC1(xA5, 5); PROC1(xA6, 6); PROC1(xA7, 7);
        LOADG(xA0,xA1,xA2,xA3,xA4,xA5,xA6,xA7, 2);
        PROC1(xB0, 8); PROC1(xB1, 9); PROC1(xB2,10); PROC1(xB3,11);
        PROC1(xB4,12); PROC1(xB5,13); PROC1(xB6,14); PROC1(xB7,15);
        LOADG(xB0,xB1,xB2,xB3,xB4,xB5,xB6,xB7, 3);
        PROC1(xA0,16); PROC1(xA1,17); PROC1(xA2,18); PROC1(xA3,19);
        PROC1(xA4,20); PROC1(xA5,21); PROC1(xA6,22); PROC1(xA7,23);
        PROC1(xB0,24); PROC1(xB1,25); PROC1(xB2,26); PROC1(xB3,27);
        PROC1(xB4,28); PROC1(xB5,29); PROC1(xB6,30); PROC1(xB7,31);

        atomicAdd(&hpre[(size_t)cur * D + c0], acc.x);
        atomicAdd(&hpre[(size_t)cur * D + c0 + 1], acc.y);
#undef LOADG
#undef PROC1
    }
}

// ---------------- fused MLP pair (MFMA) ----------------

__global__ __launch_bounds__(256, 5)
void mlp2_kernel(const float* __restrict__ in,
                 const unsigned short* __restrict__ W1h, const unsigned short* __restrict__ W1l,
                 const float* __restrict__ b1,
                 const unsigned short* __restrict__ W2h, const unsigned short* __restrict__ W2l,
                 const float* __restrict__ b2,
                 float* __restrict__ out, int relu2)
{
    __shared__ unsigned short sHi[64 * D];   // 16384 B, swizzled rows
    __shared__ unsigned short sLo[64 * D];
    const int t = threadIdx.x;
    const int n0 = blockIdx.x * 64;

    {
        const int r = t >> 2, k0 = (t & 3) * 32;
        const int gr = n0 + r;
        const int swz = (r & 7) << 3;
        #pragma unroll
        for (int j = 0; j < 4; ++j) {
            s16x8 vh = {0,0,0,0,0,0,0,0}, vl = {0,0,0,0,0,0,0,0};
            if (gr < N_NODES) {
                const float4* s4 = (const float4*)&in[(size_t)gr * D + k0];
                float4 va = s4[j * 2], vb = s4[j * 2 + 1];
                float f[8] = {va.x, va.y, va.z, va.w, vb.x, vb.y, vb.z, vb.w};
                #pragma unroll
                for (int q = 0; q < 8; ++q) {
                    unsigned short h = f2bf(f[q]);
                    vh[q] = (short)h;
                    vl[q] = (short)f2bf(f[q] - bf2f(h));
                }
            }
            *(s16x8*)&sHi[(r * D + k0 + j * 8) ^ swz] = vh;
            *(s16x8*)&sLo[(r * D + k0 + j * 8) ^ swz] = vl;
        }
    }
    __syncthreads();

    const int w = t >> 6, l = t & 63;
    const int li = l & 15, lk = l >> 4;
    const int row0 = w * 16;

    s16x8 Ah[4], Al[4];
    #pragma unroll
    for (int s = 0; s < 4; ++s) {
        const int row = row0 + li;
        const int idx = (row * D + s * 32 + lk * 8) ^ ((row & 7) << 3);
        Ah[s] = *(const s16x8*)&sHi[idx];
        Al[s] = *(const s16x8*)&sLo[idx];
    }
    __syncthreads();

    #pragma unroll
    for (int c = 0; c < 8; ++c) {
        const int col = c * 16 + li;
        f32x4 acc = {0.f, 0.f, 0.f, 0.f};
        #pragma unroll
        for (int s = 0; s < 4; ++s) {
            const s16x8 Bh = *(const s16x8*)&W1h[col * D + s * 32 + lk * 8];
            const s16x8 Bl = *(const s16x8*)&W1l[col * D + s * 32 + lk * 8];
            acc = MFMA16(Ah[s], Bh, acc, 0, 0, 0);
            acc = MFMA16(Ah[s], Bl, acc, 0, 0, 0);
            acc = MFMA16(Al[s], Bh, acc, 0, 0, 0);
        }
        const float bb = b1[col];
        #pragma unroll
        for (int reg = 0; reg < 4; ++reg) {
            const int row = row0 + lk * 4 + reg;
            float v = fmaxf(acc[reg] + bb, 0.f);
            unsigned short h = f2bf(v);
            const int idx = (row * D + col) ^ ((row & 7) << 3);
            sHi[idx] = h;
            sLo[idx] = f2bf(v - bf2f(h));
        }
    }
    __syncthreads();

    s16x8 Ch[4], Cl[4];
    #pragma unroll
    for (int s = 0; s < 4; ++s) {
        const int row = row0 + li;
        const int idx = (row * D + s * 32 + lk * 8) ^ ((row & 7) << 3);
        Ch[s] = *(const s16x8*)&sHi[idx];
        Cl[s] = *(const s16x8*)&sLo[idx];
    }

    #pragma unroll
    for (int c = 0; c < 8; ++c) {
        const int col = c * 16 + li;
        f32x4 acc = {0.f, 0.f, 0.f, 0.f};
        #pragma unroll
        for (int s = 0; s < 4; ++s) {
            const s16x8 Bh = *(const s16x8*)&W2h[col * D + s * 32 + lk * 8];
            const s16x8 Bl = *(const s16x8*)&W2l[col * D + s * 32 + lk * 8];
            acc = MFMA16(Ch[s], Bh, acc, 0, 0, 0);
            acc = MFMA16(Ch[s], Bl, acc, 0, 0, 0);
            acc = MFMA16(Cl[s], Bh, acc, 0, 0, 0);
        }
        const float bb = b2[col];
        #pragma unroll
        for (int reg = 0; reg < 4; ++reg) {
            const int gr = n0 + row0 + lk * 4 + reg;
            if (gr < N_NODES) {
                float v = acc[reg] + bb;
                if (relu2) v = fmaxf(v, 0.f);
                out[(size_t)gr * D + col] = v;
            }
        }
    }
}

// ---------------- host ----------------

extern "C" void kernel_launch(void* const* d_in, const int* in_sizes, int n_in,
                              void* d_out, int out_size, void* d_ws, size_t ws_size,
                              hipStream_t stream) {
    const float* x  = (const float*)d_in[0];
    const int*   ei = (const int*)d_in[1];
    const float* ea = (const float*)d_in[2];
    const float* We = (const float*)d_in[3];
    const float* be = (const float*)d_in[4];
    const float* W1 = (const float*)d_in[5];
    const float* b1 = (const float*)d_in[6];
    const float* W2 = (const float*)d_in[7];
    const float* b2 = (const float*)d_in[8];
    float* out = (float*)d_out;

    const int* src = ei;
    const int* dst = ei + N_EDGES;

    char* ws = (char*)d_ws;
    size_t off = 0;
    auto alloc = [&](size_t bytes) -> char* {
        char* p = ws + off;
        off = (off + bytes + 255) & ~(size_t)255;
        return p;
    };
    float* P          = (float*)alloc((size_t)N_NODES * D * 4);
    float* H          = (float*)alloc((size_t)N_NODES * D * 4);
    int*   perm       = (int*)alloc((size_t)N_EDGES * 4);
    int*   row_start  = (int*)alloc((size_t)(N_NODES + 1) * 4);
    int*   cursor     = (int*)alloc((size_t)N_NODES * 4);
    int*   srcd       = (int*)alloc((size_t)N_EDGES * 4);
    int*   dstd       = (int*)alloc((size_t)N_EDGES * 4);
    unsigned short* WeThi = (unsigned short*)alloc((size_t)NLAYERS * D * ED * 2);
    unsigned short* WeTlo = (unsigned short*)alloc((size_t)NLAYERS * D * ED * 2);
    unsigned short* W1Thi = (unsigned short*)alloc((size_t)NLAYERS * D * D * 2);
    unsigned short* W1Tlo = (unsigned short*)alloc((size_t)NLAYERS * D * D * 2);
    unsigned short* W2Thi = (unsigned short*)alloc((size_t)NLAYERS * D * D * 2);
    unsigned short* W2Tlo = (unsigned short*)alloc((size_t)NLAYERS * D * D * 2);
    unsigned short* eahi = (unsigned short*)alloc((size_t)N_EDGES * ED * 2);
    unsigned short* ealo = (unsigned short*)alloc((size_t)N_EDGES * ED * 2);
    bool direct = (off <= ws_size);
    (void)in_sizes; (void)n_in; (void)out_size;

    hipMemsetAsync(cursor, 0, N_NODES * 4, stream);
    hist_kernel<<<(N_EDGES + 255) / 256, 256, 0, stream>>>(dst, cursor);
    scan_kernel<<<1, 1024, 0, stream>>>(cursor, row_start);
    if (direct) {
        reorder_fused_kernel<<<(N_EDGES * 4 + 255) / 256, 256, 0, stream>>>(
            (const float4*)ea, src, dst, cursor, eahi, ealo, srcd, dstd);
    } else {
        scatter_kernel<<<(N_EDGES + 255) / 256, 256, 0, stream>>>(dst, cursor, perm);
        reorder_kernel<<<(N_EDGES * 4 + 255) / 256, 256, 0, stream>>>(
            (const float4*)ea, perm, src, dst, eahi, ealo, srcd, dstd);
    }
    wconvT_kernel<<<(NLAYERS * ED * D + 255) / 256, 256, 0, stream>>>(We, WeThi, WeTlo, NLAYERS, ED, D);
    wconvT_kernel<<<(NLAYERS * D * D + 255) / 256, 256, 0, stream>>>(W1, W1Thi, W1Tlo, NLAYERS, D, D);
    wconvT_kernel<<<(NLAYERS * D * D + 255) / 256, 256, 0, stream>>>(W2, W2Thi, W2Tlo, NLAYERS, D, D);

    const int ggrid = N_EDGES / 128;             // 6250
    const int mgrid = (N_NODES + 63) / 64;       // 782

    const float* X = x;
    for (int l = 0; l < NLAYERS; ++l) {
        const float* bel = be + (size_t)l * D;
        hipMemcpyAsync(P, (const void*)X, (size_t)N_NODES * D * 4,
                       hipMemcpyDeviceToDevice, stream);
        edge_fused_kernel<1><<<ggrid, 256, 0, stream>>>(X, eahi, ealo, nullptr, nullptr,
            srcd, dstd, WeThi + (size_t)l * D * ED, WeTlo + (size_t)l * D * ED, bel, P);
        float* ob = (l < NLAYERS - 1) ? H : out;
        mlp2_kernel<<<mgrid, 256, 0, stream>>>(P,
            W1Thi + (size_t)l * D * D, W1Tlo + (size_t)l * D * D, b1 + (size_t)l * D,
            W2Thi + (size_t)l * D * D, W2Tlo + (size_t)l * D * D, b2 + (size_t)l * D,
            ob, (l < NLAYERS - 1) ? 1 : 0);
        X = H;
    }
}